// Round 13
// baseline (84.295 us; speedup 1.0000x reference)
//
#include <hip/hip_runtime.h>
#include <hip/hip_bf16.h>
#include <stdint.h>

#define VOCAB 200000
#define EDIM 128
#define NTREES 2048
#define KNODES 511
#define PROJ_GRID 512

typedef __attribute__((ext_vector_type(4))) float f32x4;
typedef __attribute__((ext_vector_type(2))) float f32x2;
typedef __attribute__((ext_vector_type(8))) short s16x8;
typedef __attribute__((ext_vector_type(8))) unsigned short u16x8;
typedef __attribute__((ext_vector_type(4))) unsigned int u32x4;

#define AS1 __attribute__((address_space(1)))
#define AS3 __attribute__((address_space(3)))

__device__ __forceinline__ unsigned short f2bf(float x) {
  unsigned u = __builtin_bit_cast(unsigned, x);
  return (unsigned short)((u + 0x7fffu + ((u >> 16) & 1u)) >> 16);  // RNE
}
__device__ __forceinline__ float bf2f(unsigned short h) {
  unsigned u = ((unsigned)h) << 16;
  return __builtin_bit_cast(float, u);
}

// ---- manual OCP e4m3fn codec (fallback paths only) ----
__device__ __forceinline__ unsigned fp8enc(float v) {
  unsigned u = __builtin_bit_cast(unsigned, v);
  unsigned s = (u >> 24) & 0x80u;
  unsigned au = u & 0x7fffffffu;
  au = au > 0x43E00000u ? 0x43E00000u : au;
  unsigned r = au + 0x0007ffffu + ((au >> 20) & 1u);
  unsigned code = (((r >> 23) - 120u) << 3) | ((r >> 20) & 7u);
  float a = __builtin_bit_cast(float, au);
  unsigned sub = (unsigned)(int)rintf(a * 512.0f);
  unsigned c = (au < 0x3C800000u) ? sub : code;
  return c | s;
}
__device__ __forceinline__ float fp8dec(unsigned b) {
  unsigned e = (b >> 3) & 15u, m = b & 7u;
  float n = __builtin_bit_cast(float, ((e + 120u) << 23) | (m << 20));
  float sv = (float)(int)m * 0.001953125f;
  float v = e ? n : sv;
  return (b & 0x80u) ? -v : v;
}

__device__ __forceinline__ unsigned enc4(float a, float b, float c, float d) {
#if __has_builtin(__builtin_amdgcn_cvt_pk_fp8_f32)
  int pk = 0;
  pk = __builtin_amdgcn_cvt_pk_fp8_f32(a, b, pk, false);
  pk = __builtin_amdgcn_cvt_pk_fp8_f32(c, d, pk, true);
  return (unsigned)pk;
#else
  return fp8enc(a) | (fp8enc(b) << 8) | (fp8enc(c) << 16) | (fp8enc(d) << 24);
#endif
}

__device__ __forceinline__ void dec8(uint2 v, float* o) {
#if __has_builtin(__builtin_amdgcn_cvt_pk_f32_fp8)
  f32x2 a = __builtin_amdgcn_cvt_pk_f32_fp8(v.x, false);
  f32x2 b = __builtin_amdgcn_cvt_pk_f32_fp8(v.x, true);
  f32x2 c = __builtin_amdgcn_cvt_pk_f32_fp8(v.y, false);
  f32x2 d = __builtin_amdgcn_cvt_pk_f32_fp8(v.y, true);
  o[0] = a[0]; o[1] = a[1]; o[2] = b[0]; o[3] = b[1];
  o[4] = c[0]; o[5] = c[1]; o[6] = d[0]; o[7] = d[1];
#else
#pragma unroll
  for (int i = 0; i < 4; ++i) o[i] = fp8dec((v.x >> (8 * i)) & 0xFFu);
#pragma unroll
  for (int i = 0; i < 4; ++i) o[4 + i] = fp8dec((v.y >> (8 * i)) & 0xFFu);
#endif
}

__device__ __forceinline__ s16x8 cvt8(f32x4 a, f32x4 b) {
  u16x8 t;
#pragma unroll
  for (int i = 0; i < 4; ++i)
    t[i] = __builtin_bit_cast(unsigned short, __float2bfloat16(a[i]));
#pragma unroll
  for (int i = 0; i < 4; ++i)
    t[4 + i] = __builtin_bit_cast(unsigned short, __float2bfloat16(b[i]));
  return __builtin_bit_cast(s16x8, t);
}

// ---------------- Probe: raw read-BW of the emb array, copy-kernel style ----------------
// 4 passes x ~100.7 MB of independent f32x4 loads (6 streams/thread, 4096 blocks).
// XOR sink + per-pass base rotation defeat DCE/CSE. Appears in top-5 with its own
// dur_us -> effective read BW = 402 MB / dur. Decides ceiling-vs-structure for proj.
__global__ __launch_bounds__(256) void probe_kernel(
    const unsigned* __restrict__ src, unsigned* __restrict__ sink) {
  const long tid = (long)blockIdx.x * 256 + threadIdx.x;
  const long nthr = 4096L * 256;           // 1,048,576 threads
  const u32x4* p = (const u32x4*)src;      // 6,400,000 16B chunks total
  u32x4 x0 = {0, 0, 0, 0}, x1 = x0, x2 = x0;
#pragma unroll 1
  for (int pass = 0; pass < 4; ++pass) {
    long b = tid + pass * 7;               // rotate base: no cross-pass CSE
    u32x4 a0 = p[b];
    u32x4 a1 = p[b + nthr];
    u32x4 a2 = p[b + 2 * nthr];
    u32x4 a3 = p[b + 3 * nthr];
    u32x4 a4 = p[b + 4 * nthr];
    u32x4 a5 = p[b + 5 * nthr];            // max idx 6.29M < 6.4M
    x0 ^= a0 ^ a1;
    x1 ^= a2 ^ a3;
    x2 ^= a4 ^ a5;
  }
  u32x4 x = x0 ^ x1 ^ x2;
  unsigned r = x[0] ^ x[1] ^ x[2] ^ x[3];
  if ((threadIdx.x & 63) == 0) sink[blockIdx.x * 4 + (threadIdx.x >> 6)] = r;
}

// ---------------- Kernel 0: one-shot W/bias prep, fragment-major ----------------
__global__ __launch_bounds__(256) void wprep_kernel(
    const float* __restrict__ W, const float* __restrict__ b,
    unsigned short* __restrict__ WTb2, float* __restrict__ bsc) {
  int c = blockIdx.x * 256 + threadIdx.x;   // 0..2047
  if (c < 2048) {
    int lane = c & 63, fr = c >> 6;
    int ks = fr >> 3, nt = fr & 7, q = lane >> 4, cl = lane & 15;
    u16x8 t;
#pragma unroll
    for (int j = 0; j < 8; ++j)
      t[j] = f2bf(W[(ks * 32 + q * 8 + j) * EDIM + nt * 16 + cl] * 64.0f);
    *(u16x8*)(WTb2 + c * 8) = t;
  }
  if (c < EDIM) bsc[c] = b[c] * 64.0f;
}

// ---------------- Kernel 1: (byte-identical to R12) ----------------
__global__ __launch_bounds__(256) void proj_kernel(
    const float* __restrict__ emb, const unsigned short* __restrict__ WTb2,
    const float* __restrict__ bsc, unsigned char* __restrict__ T8) {
  __shared__ char DB[4][2][8192];     // 64 KiB: per-wave double buffer (16 rows x 512B)
  __shared__ char ST[4][16 * 144];    // 9 KiB store-stage

  const int tid = threadIdx.x;
  const int wv = tid >> 6, lane = tid & 63;
  const int q = lane >> 4, cl = lane & 15;

  s16x8 wf[32];
#pragma unroll
  for (int fr = 0; fr < 32; ++fr)
    wf[fr] = *(const s16x8*)(WTb2 + (fr * 64 + lane) * 8);
  f32x4 bb[8];
#pragma unroll
  for (int nt = 0; nt < 8; ++nt)
    bb[nt] = *(const f32x4*)(bsc + nt * 16 + q * 4);
#pragma unroll
  for (int fr = 0; fr < 32; ++fr) asm volatile("" : "+v"(wf[fr]));
#pragma unroll
  for (int nt = 0; nt < 8; ++nt) asm volatile("" : "+v"(bb[nt]));

  const int NT = VOCAB / 16;          // 12500 16-row tiles
  const int NW = PROJ_GRID * 4;       // 2048 wave-streams
  const int gw = blockIdx.x * 4 + wv;

  auto issue_dma = [&](int buf, int t) {
#pragma unroll
    for (int i = 0; i < 8; ++i) {
      int rloc = 2 * i + (lane >> 5);
      int c5 = lane & 31;
      int csrc = (c5 & 24) | ((c5 & 7) ^ (rloc & 7));
      const float* src = emb + ((long)t * 16 + rloc) * EDIM + csrc * 4;
      __builtin_amdgcn_global_load_lds(
          (const AS1 unsigned int*)src,
          (AS3 unsigned int*)(&DB[wv][buf][i * 1024]), 16, 0, 0);
    }
  };

  issue_dma(0, gw);
  issue_dma(1, gw + NW);

  int k = 0;
  for (int t = gw; t < NT; t += NW, ++k) {
    const int buf = k & 1;

    if (k == 0) {
      asm volatile("s_waitcnt vmcnt(8)" ::: "memory");
    } else if (t + NW < NT) {
      asm volatile("s_waitcnt vmcnt(12)" ::: "memory");
    } else {
      asm volatile("s_waitcnt vmcnt(4)" ::: "memory");
    }
    __builtin_amdgcn_sched_barrier(0);

    const char* rb = &DB[wv][buf][cl * 512];
    f32x4 ea[4], eb[4];
#pragma unroll
    for (int ks = 0; ks < 4; ++ks) {
      int g0 = ks * 8 + q * 2;
      int s0 = (g0 & 24) | ((g0 & 7) ^ (cl & 7));
      int g1 = g0 + 1;
      int s1 = (g1 & 24) | ((g1 & 7) ^ (cl & 7));
      ea[ks] = *(const f32x4*)(rb + s0 * 16);
      eb[ks] = *(const f32x4*)(rb + s1 * 16);
    }
    asm volatile("s_waitcnt lgkmcnt(0)" ::: "memory");
    __builtin_amdgcn_sched_barrier(0);

    const int n2 = t + 2 * NW;
    if (n2 < NT) issue_dma(buf, n2);

    f32x4 acc[8];
#pragma unroll
    for (int nt = 0; nt < 8; ++nt) acc[nt] = bb[nt];
#pragma unroll
    for (int ks = 0; ks < 4; ++ks) {
      s16x8 ef = cvt8(ea[ks], eb[ks]);
#pragma unroll
      for (int nt = 0; nt < 8; ++nt)
        acc[nt] = __builtin_amdgcn_mfma_f32_16x16x32_bf16(wf[ks * 8 + nt], ef, acc[nt], 0, 0, 0);
    }

    char* sw = &ST[wv][0] + cl * 144;
#pragma unroll
    for (int nt = 0; nt < 8; ++nt) {
      unsigned pk = enc4(acc[nt][0], acc[nt][1], acc[nt][2], acc[nt][3]);
      *(unsigned*)(sw + (nt * 4 + q) * 4) = pk;
    }
    asm volatile("s_waitcnt lgkmcnt(0)" ::: "memory");
    __builtin_amdgcn_sched_barrier(0);

    const long tb8 = (long)t * 16 * EDIM;
#pragma unroll
    for (int j = 0; j < 2; ++j) {
      const int slot = j * 64 + lane;
      const int r = slot >> 3, c16 = slot & 7;
      u32x4 v = *(const u32x4*)(&ST[wv][0] + r * 144 + c16 * 16);
      *(u32x4*)&T8[tb8 + slot * 16] = v;
    }
  }
}

// ---------------- Kernel 2: one block = one tree (unchanged — ~9 us) ----------------
__global__ __launch_bounds__(512, 4) void tree_kernel(
    const unsigned char* __restrict__ T8, const int* __restrict__ tokens,
    float* __restrict__ out) {
  __shared__ unsigned char P8[512][EDIM];          // 64 KiB
  unsigned char* lds = &P8[0][0];
  const int SOFF = 16384;
  const int MOFF = 53248;

  const int tid = threadIdx.x;
  const int tree = blockIdx.x;
  const int wv = tid >> 6, lane = tid & 63;

  const int* tk = tokens + (long)tree * KNODES;
  int toks[8];
#pragma unroll
  for (int i = 0; i < 8; ++i) {
    int node = wv * 64 + i * 8 + (lane >> 3);
    toks[i] = tk[node > 510 ? 510 : node];
  }
  const int chunk = (lane & 7) ^ ((lane >> 3) & 7);
#pragma unroll
  for (int i = 0; i < 8; ++i) {
    const unsigned char* src = T8 + (long)toks[i] * EDIM + chunk * 16;
    unsigned char* dst = &P8[wv * 64 + i * 8][0];
    __builtin_amdgcn_global_load_lds((const AS1 unsigned int*)src,
                                     (AS3 unsigned int*)dst, 16, 0, 0);
  }
  __syncthreads();

  auto ldP8 = [&](int row, int q8) -> uint2 {
    int g = q8 >> 1, h = q8 & 1;
    return *(const uint2*)(lds + row * 128 + (((g ^ (row & 7))) << 4) + h * 8);
  };
  auto saddr = [&](int slot, int q16) -> unsigned char* {
    return lds + SOFF + slot * 288 + ((q16 ^ (slot & 7)) << 4);
  };

  const int q = tid & 15;
  const int jg = tid >> 4;
  float rmax[8];
#pragma unroll
  for (int e = 0; e < 8; ++e) rmax[e] = 0.f;

  u16x8 sp7[4];
#pragma unroll
  for (int k = 0; k < 4; ++k) {
    const int p = jg + 32 * k, m = 127 + p;
    uint2 pr = ldP8(m, q);
    uint2 xr = ldP8(2 * m + 1, q);
    uint2 yr = ldP8(2 * m + 2, q);
    float pv[8], xv[8], yv[8];
    dec8(pr, pv); dec8(xr, xv); dec8(yr, yv);
#pragma unroll
    for (int e = 0; e < 8; ++e) {
      float sv = pv[e] + xv[e] + yv[e];
      rmax[e] = fmaxf(rmax[e], fmaxf(fmaxf(xv[e], yv[e]), sv));
      sp7[k][e] = f2bf(sv);
    }
  }
  __syncthreads();
#pragma unroll
  for (int k = 0; k < 4; ++k) *(u16x8*)saddr(jg + 32 * k, q) = sp7[k];
  __syncthreads();

  for (int l = 6; l >= 0; --l) {
    const int cnt = 1 << l;
    for (int p = jg; p < cnt; p += 32) {
      const int m = cnt - 1 + p;
      const int ps = p << (7 - l);
      const int c2s = ps + (1 << (6 - l));
      uint2 pr = ldP8(m, q);
      u16x8 c1 = *(const u16x8*)saddr(ps, q);
      u16x8 c2 = *(const u16x8*)saddr(c2s, q);
      float pv[8];
      dec8(pr, pv);
      u16x8 sp;
#pragma unroll
      for (int e = 0; e < 8; ++e) {
        float sv = pv[e] + bf2f(c1[e]) + bf2f(c2[e]);
        rmax[e] = fmaxf(rmax[e], sv);
        sp[e] = f2bf(sv);
      }
      *(u16x8*)saddr(ps, q) = sp;
    }
    __syncthreads();
  }

#pragma unroll
  for (int e = 0; e < 8; ++e) {
    rmax[e] = fmaxf(rmax[e], __shfl_xor(rmax[e], 16, 64));
    rmax[e] = fmaxf(rmax[e], __shfl_xor(rmax[e], 32, 64));
  }
  float* mb = (float*)(lds + MOFF);
  if (lane < 16) {
#pragma unroll
    for (int e = 0; e < 8; ++e) mb[wv * 128 + lane * 8 + e] = rmax[e];
  }
  __syncthreads();
  if (tid < 128) {
    float v = mb[tid];
#pragma unroll
    for (int w2 = 1; w2 < 8; ++w2) v = fmaxf(v, mb[w2 * 128 + tid]);
    out[(long)tree * 128 + tid] = v * 0.015625f;
  }
}

extern "C" void kernel_launch(void* const* d_in, const int* in_sizes, int n_in,
                              void* d_out, int out_size, void* d_ws, size_t ws_size,
                              hipStream_t stream) {
  const float* emb = (const float*)d_in[0];
  const float* W = (const float*)d_in[1];
  const float* b = (const float*)d_in[2];
  const int* tokens = (const int*)d_in[3];

  unsigned char* T8 = (unsigned char*)d_ws;                          // 25.6 MB
  unsigned short* WTb2 = (unsigned short*)((char*)d_ws + 25600000);  // 32 KB
  float* bsc = (float*)((char*)d_ws + 25632768);                     // 512 B
  unsigned* sink = (unsigned*)((char*)d_ws + (32 << 20));            // 64 KB probe sink
  float* out = (float*)d_out;

  probe_kernel<<<4096, 256, 0, stream>>>((const unsigned*)emb, sink);
  wprep_kernel<<<8, 256, 0, stream>>>(W, b, WTb2, bsc);
  proj_kernel<<<PROJ_GRID, 256, 0, stream>>>(emb, WTb2, bsc, T8);
  tree_kernel<<<NTREES, 512, 0, stream>>>(T8, tokens, out);
}

// Round 14
// 79.284 us; speedup vs baseline: 1.0632x; 1.0632x over previous
//
#include <hip/hip_runtime.h>
#include <hip/hip_bf16.h>
#include <stdint.h>

#define VOCAB 200000
#define EDIM 128
#define NTREES 2048
#define KNODES 511

typedef __attribute__((ext_vector_type(4))) float f32x4;
typedef __attribute__((ext_vector_type(2))) float f32x2;
typedef __attribute__((ext_vector_type(8))) short s16x8;
typedef __attribute__((ext_vector_type(8))) unsigned short u16x8;
typedef __attribute__((ext_vector_type(4))) unsigned int u32x4;

#define AS1 __attribute__((address_space(1)))
#define AS3 __attribute__((address_space(3)))

__device__ __forceinline__ unsigned short f2bf(float x) {
  unsigned u = __builtin_bit_cast(unsigned, x);
  return (unsigned short)((u + 0x7fffu + ((u >> 16) & 1u)) >> 16);  // RNE
}
__device__ __forceinline__ float bf2f(unsigned short h) {
  unsigned u = ((unsigned)h) << 16;
  return __builtin_bit_cast(float, u);
}

// ---- manual OCP e4m3fn codec (fallback paths only) ----
__device__ __forceinline__ unsigned fp8enc(float v) {
  unsigned u = __builtin_bit_cast(unsigned, v);
  unsigned s = (u >> 24) & 0x80u;
  unsigned au = u & 0x7fffffffu;
  au = au > 0x43E00000u ? 0x43E00000u : au;
  unsigned r = au + 0x0007ffffu + ((au >> 20) & 1u);
  unsigned code = (((r >> 23) - 120u) << 3) | ((r >> 20) & 7u);
  float a = __builtin_bit_cast(float, au);
  unsigned sub = (unsigned)(int)rintf(a * 512.0f);
  unsigned c = (au < 0x3C800000u) ? sub : code;
  return c | s;
}
__device__ __forceinline__ float fp8dec(unsigned b) {
  unsigned e = (b >> 3) & 15u, m = b & 7u;
  float n = __builtin_bit_cast(float, ((e + 120u) << 23) | (m << 20));
  float sv = (float)(int)m * 0.001953125f;
  float v = e ? n : sv;
  return (b & 0x80u) ? -v : v;
}

__device__ __forceinline__ unsigned enc4(float a, float b, float c, float d) {
#if __has_builtin(__builtin_amdgcn_cvt_pk_fp8_f32)
  int pk = 0;
  pk = __builtin_amdgcn_cvt_pk_fp8_f32(a, b, pk, false);
  pk = __builtin_amdgcn_cvt_pk_fp8_f32(c, d, pk, true);
  return (unsigned)pk;
#else
  return fp8enc(a) | (fp8enc(b) << 8) | (fp8enc(c) << 16) | (fp8enc(d) << 24);
#endif
}

__device__ __forceinline__ void dec8(uint2 v, float* o) {
#if __has_builtin(__builtin_amdgcn_cvt_pk_f32_fp8)
  f32x2 a = __builtin_amdgcn_cvt_pk_f32_fp8(v.x, false);
  f32x2 b = __builtin_amdgcn_cvt_pk_f32_fp8(v.x, true);
  f32x2 c = __builtin_amdgcn_cvt_pk_f32_fp8(v.y, false);
  f32x2 d = __builtin_amdgcn_cvt_pk_f32_fp8(v.y, true);
  o[0] = a[0]; o[1] = a[1]; o[2] = b[0]; o[3] = b[1];
  o[4] = c[0]; o[5] = c[1]; o[6] = d[0]; o[7] = d[1];
#else
#pragma unroll
  for (int i = 0; i < 4; ++i) o[i] = fp8dec((v.x >> (8 * i)) & 0xFFu);
#pragma unroll
  for (int i = 0; i < 4; ++i) o[4 + i] = fp8dec((v.y >> (8 * i)) & 0xFFu);
#endif
}

// ---------------- Kernel 0: one-shot W/bias prep, fragment-major ----------------
__global__ __launch_bounds__(256) void wprep_kernel(
    const float* __restrict__ W, const float* __restrict__ b,
    unsigned short* __restrict__ WTb2, float* __restrict__ bsc) {
  int c = blockIdx.x * 256 + threadIdx.x;   // 0..2047
  if (c < 2048) {
    int lane = c & 63, fr = c >> 6;
    int ks = fr >> 3, nt = fr & 7, q = lane >> 4, cl = lane & 15;
    u16x8 t;
#pragma unroll
    for (int j = 0; j < 8; ++j)
      t[j] = f2bf(W[(ks * 32 + q * 8 + j) * EDIM + nt * 16 + cl] * 64.0f);
    *(u16x8*)(WTb2 + c * 8) = t;
  }
  if (c < EDIM) bsc[c] = b[c] * 64.0f;
}

// ---------------- Kernel 1a: Tbf = bf16(emb) — probe-shaped streaming cast ----------------
// 8 independent f32x4 loads/thread (batched, one join), 4 x 16B stores. 3200 blocks.
__global__ __launch_bounds__(256) void cast_kernel(
    const float* __restrict__ src, unsigned short* __restrict__ dst) {
  const long t = (long)blockIdx.x * 256 + threadIdx.x;   // 819200 threads
  const long NCH = 3200000;                              // 8-elem chunks total
  const long nthr = 3200L * 256;
  long idx[4];
  f32x4 a[4], b[4];
#pragma unroll
  for (int j = 0; j < 4; ++j) {
    long c = t + j * nthr;
    idx[j] = c < NCH ? c : (NCH - 1);                    // tail: dup chunk (same value)
    a[j] = *(const f32x4*)(src + idx[j] * 8);
    b[j] = *(const f32x4*)(src + idx[j] * 8 + 4);
  }
#pragma unroll
  for (int j = 0; j < 4; ++j) {
    u16x8 o;
#pragma unroll
    for (int i = 0; i < 4; ++i) o[i] = f2bf(a[j][i]);
#pragma unroll
    for (int i = 0; i < 4; ++i) o[4 + i] = f2bf(b[j][i]);
    *(u16x8*)(dst + idx[j] * 8) = o;
  }
}

// ---------------- Kernel 1b: T8 = fp8( Tbf @ W*64 + b*64 ) — one-shot GEMM ----------------
// One 128-row tile per block, NO loop. A-fragments (bf16) are direct 16B loads in MFMA
// layout, issued before the W-staging barrier and pinned. W via LDS ds_read (lgkmcnt
// queue, not vmcnt). Staged coalesced stores (4KB/wave).
__global__ __launch_bounds__(256, 3) void gemm_kernel(
    const unsigned short* __restrict__ Tbf, const unsigned short* __restrict__ WTb2,
    const float* __restrict__ bsc, unsigned char* __restrict__ T8) {
  __shared__ unsigned short WL[2048 * 8];   // 32 KiB fragment-major
  __shared__ float LB[EDIM];                // 512 B
  __shared__ char ST[4][32 * 144];          // 18 KiB store stage

  const int tid = threadIdx.x;
  const int wv = tid >> 6, lane = tid & 63;
  const int q = lane >> 4, cl = lane & 15;

  // stage W into LDS (8 x 1KB DMA per wave, linear dest) + bias
#pragma unroll
  for (int i = 0; i < 8; ++i) {
    const char* src = (const char*)WTb2 + wv * 8192 + i * 1024 + lane * 16;
    char* dstp = (char*)WL + wv * 8192 + i * 1024;
    __builtin_amdgcn_global_load_lds((const AS1 unsigned int*)src,
                                     (AS3 unsigned int*)dstp, 16, 0, 0);
  }
  if (tid < EDIM) LB[tid] = bsc[tid];

  // issue ALL 8 A-fragment loads now (independent; land while W stages)
  const long rowbase = (long)blockIdx.x * 128 + wv * 32;
  long r0 = rowbase + cl, r1 = rowbase + 16 + cl;
  if (r0 >= VOCAB) r0 = VOCAB - 1;          // tail: dup loads, stores masked
  if (r1 >= VOCAB) r1 = VOCAB - 1;
  s16x8 ef[2][4];
#pragma unroll
  for (int ks = 0; ks < 4; ++ks) {
    ef[0][ks] = *(const s16x8*)(Tbf + r0 * EDIM + ks * 32 + q * 8);
    ef[1][ks] = *(const s16x8*)(Tbf + r1 * EDIM + ks * 32 + q * 8);
  }
#pragma unroll
  for (int rt = 0; rt < 2; ++rt)
#pragma unroll
    for (int ks = 0; ks < 4; ++ks) asm volatile("" : "+v"(ef[rt][ks]));

  __syncthreads();                          // W + ef all landed

  f32x4 acc[2][8];
#pragma unroll
  for (int nt = 0; nt < 8; ++nt) {
    f32x4 bv = *(const f32x4*)(LB + nt * 16 + q * 4);
    acc[0][nt] = bv;
    acc[1][nt] = bv;
  }
#pragma unroll
  for (int ks = 0; ks < 4; ++ks) {
#pragma unroll
    for (int nt = 0; nt < 8; ++nt) {
      s16x8 wf = *(const s16x8*)((const char*)WL + (ks * 8 + nt) * 1024 + lane * 16);
      acc[0][nt] = __builtin_amdgcn_mfma_f32_16x16x32_bf16(wf, ef[0][ks], acc[0][nt], 0, 0, 0);
      acc[1][nt] = __builtin_amdgcn_mfma_f32_16x16x32_bf16(wf, ef[1][ks], acc[1][nt], 0, 0, 0);
    }
  }

  // stage fp8 (row rt*16+cl, u32 col nt*4+q), pitch 144B
  char* sw = &ST[wv][0];
#pragma unroll
  for (int rt = 0; rt < 2; ++rt)
#pragma unroll
    for (int nt = 0; nt < 8; ++nt) {
      unsigned pk = enc4(acc[rt][nt][0], acc[rt][nt][1], acc[rt][nt][2], acc[rt][nt][3]);
      *(unsigned*)(sw + (rt * 16 + cl) * 144 + (nt * 4 + q) * 4) = pk;
    }
  asm volatile("s_waitcnt lgkmcnt(0)" ::: "memory");
  __builtin_amdgcn_sched_barrier(0);

  // drain: 4 x (ds_read_b128 + 16B store), 4KB contiguous per wave
#pragma unroll
  for (int j = 0; j < 4; ++j) {
    const int slot = j * 64 + lane;         // 0..255
    const int rr = slot >> 3, c16 = slot & 7;
    const long grow = rowbase + rr;
    if (grow < VOCAB) {
      u32x4 v = *(const u32x4*)(sw + rr * 144 + c16 * 16);
      *(u32x4*)&T8[grow * EDIM + c16 * 16] = v;
    }
  }
}

// ---------------- Kernel 2: one block = one tree (unchanged — ~9 us) ----------------
__global__ __launch_bounds__(512, 4) void tree_kernel(
    const unsigned char* __restrict__ T8, const int* __restrict__ tokens,
    float* __restrict__ out) {
  __shared__ unsigned char P8[512][EDIM];          // 64 KiB
  unsigned char* lds = &P8[0][0];
  const int SOFF = 16384;
  const int MOFF = 53248;

  const int tid = threadIdx.x;
  const int tree = blockIdx.x;
  const int wv = tid >> 6, lane = tid & 63;

  const int* tk = tokens + (long)tree * KNODES;
  int toks[8];
#pragma unroll
  for (int i = 0; i < 8; ++i) {
    int node = wv * 64 + i * 8 + (lane >> 3);
    toks[i] = tk[node > 510 ? 510 : node];
  }
  const int chunk = (lane & 7) ^ ((lane >> 3) & 7);
#pragma unroll
  for (int i = 0; i < 8; ++i) {
    const unsigned char* src = T8 + (long)toks[i] * EDIM + chunk * 16;
    unsigned char* dst = &P8[wv * 64 + i * 8][0];
    __builtin_amdgcn_global_load_lds((const AS1 unsigned int*)src,
                                     (AS3 unsigned int*)dst, 16, 0, 0);
  }
  __syncthreads();

  auto ldP8 = [&](int row, int q8) -> uint2 {
    int g = q8 >> 1, h = q8 & 1;
    return *(const uint2*)(lds + row * 128 + (((g ^ (row & 7))) << 4) + h * 8);
  };
  auto saddr = [&](int slot, int q16) -> unsigned char* {
    return lds + SOFF + slot * 288 + ((q16 ^ (slot & 7)) << 4);
  };

  const int q = tid & 15;
  const int jg = tid >> 4;
  float rmax[8];
#pragma unroll
  for (int e = 0; e < 8; ++e) rmax[e] = 0.f;

  u16x8 sp7[4];
#pragma unroll
  for (int k = 0; k < 4; ++k) {
    const int p = jg + 32 * k, m = 127 + p;
    uint2 pr = ldP8(m, q);
    uint2 xr = ldP8(2 * m + 1, q);
    uint2 yr = ldP8(2 * m + 2, q);
    float pv[8], xv[8], yv[8];
    dec8(pr, pv); dec8(xr, xv); dec8(yr, yv);
#pragma unroll
    for (int e = 0; e < 8; ++e) {
      float sv = pv[e] + xv[e] + yv[e];
      rmax[e] = fmaxf(rmax[e], fmaxf(fmaxf(xv[e], yv[e]), sv));
      sp7[k][e] = f2bf(sv);
    }
  }
  __syncthreads();
#pragma unroll
  for (int k = 0; k < 4; ++k) *(u16x8*)saddr(jg + 32 * k, q) = sp7[k];
  __syncthreads();

  for (int l = 6; l >= 0; --l) {
    const int cnt = 1 << l;
    for (int p = jg; p < cnt; p += 32) {
      const int m = cnt - 1 + p;
      const int ps = p << (7 - l);
      const int c2s = ps + (1 << (6 - l));
      uint2 pr = ldP8(m, q);
      u16x8 c1 = *(const u16x8*)saddr(ps, q);
      u16x8 c2 = *(const u16x8*)saddr(c2s, q);
      float pv[8];
      dec8(pr, pv);
      u16x8 sp;
#pragma unroll
      for (int e = 0; e < 8; ++e) {
        float sv = pv[e] + bf2f(c1[e]) + bf2f(c2[e]);
        rmax[e] = fmaxf(rmax[e], sv);
        sp[e] = f2bf(sv);
      }
      *(u16x8*)saddr(ps, q) = sp;
    }
    __syncthreads();
  }

#pragma unroll
  for (int e = 0; e < 8; ++e) {
    rmax[e] = fmaxf(rmax[e], __shfl_xor(rmax[e], 16, 64));
    rmax[e] = fmaxf(rmax[e], __shfl_xor(rmax[e], 32, 64));
  }
  float* mb = (float*)(lds + MOFF);
  if (lane < 16) {
#pragma unroll
    for (int e = 0; e < 8; ++e) mb[wv * 128 + lane * 8 + e] = rmax[e];
  }
  __syncthreads();
  if (tid < 128) {
    float v = mb[tid];
#pragma unroll
    for (int w2 = 1; w2 < 8; ++w2) v = fmaxf(v, mb[w2 * 128 + tid]);
    out[(long)tree * 128 + tid] = v * 0.015625f;
  }
}

extern "C" void kernel_launch(void* const* d_in, const int* in_sizes, int n_in,
                              void* d_out, int out_size, void* d_ws, size_t ws_size,
                              hipStream_t stream) {
  const float* emb = (const float*)d_in[0];
  const float* W = (const float*)d_in[1];
  const float* b = (const float*)d_in[2];
  const int* tokens = (const int*)d_in[3];

  unsigned char* T8 = (unsigned char*)d_ws;                          // 25.6 MB @ 0
  unsigned short* Tbf = (unsigned short*)((char*)d_ws + (32 << 20)); // 51.2 MB @ 32MB
  unsigned short* WTb2 = (unsigned short*)((char*)d_ws + (96 << 20));// 32 KB @ 96MB
  float* bsc = (float*)((char*)d_ws + (96 << 20) + 32768);           // 512 B
  float* out = (float*)d_out;

  wprep_kernel<<<8, 256, 0, stream>>>(W, b, WTb2, bsc);
  cast_kernel<<<3200, 256, 0, stream>>>(emb, Tbf);
  gemm_kernel<<<1563, 256, 0, stream>>>(Tbf, WTb2, bsc, T8);
  tree_kernel<<<NTREES, 512, 0, stream>>>(T8, tokens, out);
}

// Round 15
// 64.555 us; speedup vs baseline: 1.3058x; 1.2282x over previous
//
#include <hip/hip_runtime.h>
#include <hip/hip_bf16.h>
#include <stdint.h>

#define VOCAB 200000
#define EDIM 128
#define NTREES 2048
#define KNODES 511

typedef __attribute__((ext_vector_type(4))) float f32x4;
typedef __attribute__((ext_vector_type(2))) float f32x2;
typedef __attribute__((ext_vector_type(8))) short s16x8;
typedef __attribute__((ext_vector_type(8))) unsigned short u16x8;
typedef __attribute__((ext_vector_type(4))) unsigned int u32x4;

#define AS1 __attribute__((address_space(1)))
#define AS3 __attribute__((address_space(3)))

__device__ __forceinline__ unsigned short f2bf(float x) {
  unsigned u = __builtin_bit_cast(unsigned, x);
  return (unsigned short)((u + 0x7fffu + ((u >> 16) & 1u)) >> 16);  // RNE
}
__device__ __forceinline__ float bf2f(unsigned short h) {
  unsigned u = ((unsigned)h) << 16;
  return __builtin_bit_cast(float, u);
}

// ---- manual OCP e4m3fn codec (fallback paths only) ----
__device__ __forceinline__ unsigned fp8enc(float v) {
  unsigned u = __builtin_bit_cast(unsigned, v);
  unsigned s = (u >> 24) & 0x80u;
  unsigned au = u & 0x7fffffffu;
  au = au > 0x43E00000u ? 0x43E00000u : au;
  unsigned r = au + 0x0007ffffu + ((au >> 20) & 1u);
  unsigned code = (((r >> 23) - 120u) << 3) | ((r >> 20) & 7u);
  float a = __builtin_bit_cast(float, au);
  unsigned sub = (unsigned)(int)rintf(a * 512.0f);
  unsigned c = (au < 0x3C800000u) ? sub : code;
  return c | s;
}
__device__ __forceinline__ float fp8dec(unsigned b) {
  unsigned e = (b >> 3) & 15u, m = b & 7u;
  float n = __builtin_bit_cast(float, ((e + 120u) << 23) | (m << 20));
  float sv = (float)(int)m * 0.001953125f;
  float v = e ? n : sv;
  return (b & 0x80u) ? -v : v;
}

__device__ __forceinline__ unsigned enc4(float a, float b, float c, float d) {
#if __has_builtin(__builtin_amdgcn_cvt_pk_fp8_f32)
  int pk = 0;
  pk = __builtin_amdgcn_cvt_pk_fp8_f32(a, b, pk, false);
  pk = __builtin_amdgcn_cvt_pk_fp8_f32(c, d, pk, true);
  return (unsigned)pk;
#else
  return fp8enc(a) | (fp8enc(b) << 8) | (fp8enc(c) << 16) | (fp8enc(d) << 24);
#endif
}

__device__ __forceinline__ void dec8(uint2 v, float* o) {
#if __has_builtin(__builtin_amdgcn_cvt_pk_f32_fp8)
  f32x2 a = __builtin_amdgcn_cvt_pk_f32_fp8(v.x, false);
  f32x2 b = __builtin_amdgcn_cvt_pk_f32_fp8(v.x, true);
  f32x2 c = __builtin_amdgcn_cvt_pk_f32_fp8(v.y, false);
  f32x2 d = __builtin_amdgcn_cvt_pk_f32_fp8(v.y, true);
  o[0] = a[0]; o[1] = a[1]; o[2] = b[0]; o[3] = b[1];
  o[4] = c[0]; o[5] = c[1]; o[6] = d[0]; o[7] = d[1];
#else
#pragma unroll
  for (int i = 0; i < 4; ++i) o[i] = fp8dec((v.x >> (8 * i)) & 0xFFu);
#pragma unroll
  for (int i = 0; i < 4; ++i) o[4 + i] = fp8dec((v.y >> (8 * i)) & 0xFFu);
#endif
}

__device__ __forceinline__ s16x8 cvt8(f32x4 a, f32x4 b) {
  u16x8 t;
#pragma unroll
  for (int i = 0; i < 4; ++i)
    t[i] = __builtin_bit_cast(unsigned short, __float2bfloat16(a[i]));
#pragma unroll
  for (int i = 0; i < 4; ++i)
    t[4 + i] = __builtin_bit_cast(unsigned short, __float2bfloat16(b[i]));
  return __builtin_bit_cast(s16x8, t);
}

// ---------------- Kernel 0: one-shot W/bias prep, fragment-major ----------------
__global__ __launch_bounds__(256) void wprep_kernel(
    const float* __restrict__ W, const float* __restrict__ b,
    unsigned short* __restrict__ WTb2, float* __restrict__ bsc) {
  int c = blockIdx.x * 256 + threadIdx.x;   // 0..2047
  if (c < 2048) {
    int lane = c & 63, fr = c >> 6;
    int ks = fr >> 3, nt = fr & 7, q = lane >> 4, cl = lane & 15;
    u16x8 t;
#pragma unroll
    for (int j = 0; j < 8; ++j)
      t[j] = f2bf(W[(ks * 32 + q * 8 + j) * EDIM + nt * 16 + cl] * 64.0f);
    *(u16x8*)(WTb2 + c * 8) = t;
  }
  if (c < EDIM) bsc[c] = b[c] * 64.0f;
}

// ---------------- Kernel 1: T8 = fp8( emb @ W*64 + b*64 ) — one-shot, merged ----------------
// One 128-row tile per block (1563 blocks, no loop, no cast round-trip). ALL memory
// issued up front: 16 independent emb f32x4 loads/thread + 8 W-DMAs/wave; ONE join
// (__syncthreads drains vmcnt once — fence also stops loads sinking). Then 32 MFMAs
// fed purely from registers/LDS, fp8 encode, staged 4KB-coalesced stores.
__global__ __launch_bounds__(256, 3) void proj_kernel(
    const float* __restrict__ emb, const unsigned short* __restrict__ WTb2,
    const float* __restrict__ bsc, unsigned char* __restrict__ T8) {
  __shared__ unsigned short WL[2048 * 8];   // 32 KiB fragment-major
  __shared__ float LB[EDIM];                // 512 B
  __shared__ char ST[4][32 * 144];          // 18 KiB store stage

  const int tid = threadIdx.x;
  const int wv = tid >> 6, lane = tid & 63;
  const int q = lane >> 4, cl = lane & 15;

  // issue the block's emb working set: 16 independent f32x4 loads per thread
  const long rowbase = (long)blockIdx.x * 128 + wv * 32;
  long r0 = rowbase + cl, r1 = rowbase + 16 + cl;
  if (r0 >= VOCAB) r0 = VOCAB - 1;          // tail: dup LOADS only (broadcast-safe)
  if (r1 >= VOCAB) r1 = VOCAB - 1;
  const float* p0 = emb + r0 * EDIM + q * 8;
  const float* p1 = emb + r1 * EDIM + q * 8;
  f32x4 ea0[4], eb0[4], ea1[4], eb1[4];
#pragma unroll
  for (int ks = 0; ks < 4; ++ks) {
    ea0[ks] = *(const f32x4*)(p0 + ks * 32);
    eb0[ks] = *(const f32x4*)(p0 + ks * 32 + 4);
    ea1[ks] = *(const f32x4*)(p1 + ks * 32);
    eb1[ks] = *(const f32x4*)(p1 + ks * 32 + 4);
  }

  // stage W into LDS (8 x 1KB DMA per wave, linear dest) + bias
#pragma unroll
  for (int i = 0; i < 8; ++i) {
    const char* src = (const char*)WTb2 + wv * 8192 + i * 1024 + lane * 16;
    char* dstp = (char*)WL + wv * 8192 + i * 1024;
    __builtin_amdgcn_global_load_lds((const AS1 unsigned int*)src,
                                     (AS3 unsigned int*)dstp, 16, 0, 0);
  }
  if (tid < EDIM) LB[tid] = bsc[tid];

  __syncthreads();                          // the ONE vmcnt join: emb + W landed

  f32x4 acc[2][8];
#pragma unroll
  for (int nt = 0; nt < 8; ++nt) {
    f32x4 bv = *(const f32x4*)(LB + nt * 16 + q * 4);
    acc[0][nt] = bv;
    acc[1][nt] = bv;
  }
#pragma unroll
  for (int ks = 0; ks < 4; ++ks) {
    s16x8 ef0 = cvt8(ea0[ks], eb0[ks]);
    s16x8 ef1 = cvt8(ea1[ks], eb1[ks]);
#pragma unroll
    for (int nt = 0; nt < 8; ++nt) {
      s16x8 wf = *(const s16x8*)((const char*)WL + (ks * 8 + nt) * 1024 + lane * 16);
      acc[0][nt] = __builtin_amdgcn_mfma_f32_16x16x32_bf16(wf, ef0, acc[0][nt], 0, 0, 0);
      acc[1][nt] = __builtin_amdgcn_mfma_f32_16x16x32_bf16(wf, ef1, acc[1][nt], 0, 0, 0);
    }
  }

  // stage fp8 (row rt*16+cl, u32 col nt*4+q), pitch 144B
  char* sw = &ST[wv][0];
#pragma unroll
  for (int rt = 0; rt < 2; ++rt)
#pragma unroll
    for (int nt = 0; nt < 8; ++nt) {
      unsigned pk = enc4(acc[rt][nt][0], acc[rt][nt][1], acc[rt][nt][2], acc[rt][nt][3]);
      *(unsigned*)(sw + (rt * 16 + cl) * 144 + (nt * 4 + q) * 4) = pk;
    }
  asm volatile("s_waitcnt lgkmcnt(0)" ::: "memory");
  __builtin_amdgcn_sched_barrier(0);

  // drain: 4 x (ds_read_b128 + 16B store), 4KB contiguous per wave; tail masked
#pragma unroll
  for (int j = 0; j < 4; ++j) {
    const int slot = j * 64 + lane;         // 0..255
    const int rr = slot >> 3, c16 = slot & 7;
    const long grow = rowbase + rr;
    if (grow < VOCAB) {
      u32x4 v = *(const u32x4*)(sw + rr * 144 + c16 * 16);
      *(u32x4*)&T8[grow * EDIM + c16 * 16] = v;
    }
  }
}

// ---------------- Kernel 2: one block = one tree (unchanged — ~9 us) ----------------
__global__ __launch_bounds__(512, 4) void tree_kernel(
    const unsigned char* __restrict__ T8, const int* __restrict__ tokens,
    float* __restrict__ out) {
  __shared__ unsigned char P8[512][EDIM];          // 64 KiB
  unsigned char* lds = &P8[0][0];
  const int SOFF = 16384;
  const int MOFF = 53248;

  const int tid = threadIdx.x;
  const int tree = blockIdx.x;
  const int wv = tid >> 6, lane = tid & 63;

  const int* tk = tokens + (long)tree * KNODES;
  int toks[8];
#pragma unroll
  for (int i = 0; i < 8; ++i) {
    int node = wv * 64 + i * 8 + (lane >> 3);
    toks[i] = tk[node > 510 ? 510 : node];
  }
  const int chunk = (lane & 7) ^ ((lane >> 3) & 7);
#pragma unroll
  for (int i = 0; i < 8; ++i) {
    const unsigned char* src = T8 + (long)toks[i] * EDIM + chunk * 16;
    unsigned char* dst = &P8[wv * 64 + i * 8][0];
    __builtin_amdgcn_global_load_lds((const AS1 unsigned int*)src,
                                     (AS3 unsigned int*)dst, 16, 0, 0);
  }
  __syncthreads();

  auto ldP8 = [&](int row, int q8) -> uint2 {
    int g = q8 >> 1, h = q8 & 1;
    return *(const uint2*)(lds + row * 128 + (((g ^ (row & 7))) << 4) + h * 8);
  };
  auto saddr = [&](int slot, int q16) -> unsigned char* {
    return lds + SOFF + slot * 288 + ((q16 ^ (slot & 7)) << 4);
  };

  const int q = tid & 15;
  const int jg = tid >> 4;
  float rmax[8];
#pragma unroll
  for (int e = 0; e < 8; ++e) rmax[e] = 0.f;

  u16x8 sp7[4];
#pragma unroll
  for (int k = 0; k < 4; ++k) {
    const int p = jg + 32 * k, m = 127 + p;
    uint2 pr = ldP8(m, q);
    uint2 xr = ldP8(2 * m + 1, q);
    uint2 yr = ldP8(2 * m + 2, q);
    float pv[8], xv[8], yv[8];
    dec8(pr, pv); dec8(xr, xv); dec8(yr, yv);
#pragma unroll
    for (int e = 0; e < 8; ++e) {
      float sv = pv[e] + xv[e] + yv[e];
      rmax[e] = fmaxf(rmax[e], fmaxf(fmaxf(xv[e], yv[e]), sv));
      sp7[k][e] = f2bf(sv);
    }
  }
  __syncthreads();
#pragma unroll
  for (int k = 0; k < 4; ++k) *(u16x8*)saddr(jg + 32 * k, q) = sp7[k];
  __syncthreads();

  for (int l = 6; l >= 0; --l) {
    const int cnt = 1 << l;
    for (int p = jg; p < cnt; p += 32) {
      const int m = cnt - 1 + p;
      const int ps = p << (7 - l);
      const int c2s = ps + (1 << (6 - l));
      uint2 pr = ldP8(m, q);
      u16x8 c1 = *(const u16x8*)saddr(ps, q);
      u16x8 c2 = *(const u16x8*)saddr(c2s, q);
      float pv[8];
      dec8(pr, pv);
      u16x8 sp;
#pragma unroll
      for (int e = 0; e < 8; ++e) {
        float sv = pv[e] + bf2f(c1[e]) + bf2f(c2[e]);
        rmax[e] = fmaxf(rmax[e], sv);
        sp[e] = f2bf(sv);
      }
      *(u16x8*)saddr(ps, q) = sp;
    }
    __syncthreads();
  }

#pragma unroll
  for (int e = 0; e < 8; ++e) {
    rmax[e] = fmaxf(rmax[e], __shfl_xor(rmax[e], 16, 64));
    rmax[e] = fmaxf(rmax[e], __shfl_xor(rmax[e], 32, 64));
  }
  float* mb = (float*)(lds + MOFF);
  if (lane < 16) {
#pragma unroll
    for (int e = 0; e < 8; ++e) mb[wv * 128 + lane * 8 + e] = rmax[e];
  }
  __syncthreads();
  if (tid < 128) {
    float v = mb[tid];
#pragma unroll
    for (int w2 = 1; w2 < 8; ++w2) v = fmaxf(v, mb[w2 * 128 + tid]);
    out[(long)tree * 128 + tid] = v * 0.015625f;
  }
}

extern "C" void kernel_launch(void* const* d_in, const int* in_sizes, int n_in,
                              void* d_out, int out_size, void* d_ws, size_t ws_size,
                              hipStream_t stream) {
  const float* emb = (const float*)d_in[0];
  const float* W = (const float*)d_in[1];
  const float* b = (const float*)d_in[2];
  const int* tokens = (const int*)d_in[3];

  unsigned char* T8 = (unsigned char*)d_ws;                           // 25.6 MB @ 0
  unsigned short* WTb2 = (unsigned short*)((char*)d_ws + (32 << 20)); // 32 KB @ 32MB
  float* bsc = (float*)((char*)d_ws + (32 << 20) + 32768);            // 512 B
  float* out = (float*)d_out;

  wprep_kernel<<<8, 256, 0, stream>>>(W, b, WTb2, bsc);
  proj_kernel<<<1563, 256, 0, stream>>>(emb, WTb2, bsc, T8);
  tree_kernel<<<NTREES, 512, 0, stream>>>(T8, tokens, out);
}